// Round 2
// baseline (307.270 us; speedup 1.0000x reference)
//
#include <hip/hip_runtime.h>
#include <math.h>

#define TPB 256

// statsBuf layout (floats): [0:64) bn1 sum, [64:128) bn1 sumsq,
//                           [128:160) bn2 sum, [160:192) bn2 sumsq

// -------------------- segment pool: per-block LDS bins -> partial sums --------------------
// Grid: B*chunks blocks. Block (b,chunk) accumulates K*5 bins (fx,fy,xx,yy,count)
// in LDS over its pixel chunk, then writes them to partial[] with plain coalesced
// stores (no global atomics). Block 0 also zeroes the BN stats accumulators.
__global__ void pool_kernel(const int* __restrict__ labels,
                            const float* __restrict__ fx,
                            const float* __restrict__ fy,
                            float* __restrict__ partial,
                            float* __restrict__ statsBuf,
                            int K, int H, int W, int chunks) {
    extern __shared__ float bins[];            // K*5 floats
    const int P = H * W;
    const int b = blockIdx.x / chunks;
    const int chunk = blockIdx.x - b * chunks;
    const int chunkP = P / chunks;
    const int tid = threadIdx.x;

    if (blockIdx.x == 0 && tid < 192) statsBuf[tid] = 0.f;

    const int KB = K * 5;
    for (int i = tid; i < KB; i += TPB) bins[i] = 0.f;
    __syncthreads();

    const float sx = 2.f / (float)(H - 1);     // xx varies along dim 2 (i = p / W)
    const float sy = 2.f / (float)(W - 1);     // yy varies along dim 3 (j = p % W)
    const size_t base = (size_t)b * P + (size_t)chunk * chunkP;
    const int4*   l4p  = (const int4*)(labels + base);
    const float4* fx4p = (const float4*)(fx + base);
    const float4* fy4p = (const float4*)(fy + base);
    const int nvec = chunkP >> 2;

    for (int v = tid; v < nvec; v += TPB) {
        int4   l4 = l4p[v];
        float4 f4 = fx4p[v];
        float4 g4 = fy4p[v];
        int p0 = chunk * chunkP + (v << 2);
        int   ls[4] = {l4.x, l4.y, l4.z, l4.w};
        float fs[4] = {f4.x, f4.y, f4.z, f4.w};
        float gs[4] = {g4.x, g4.y, g4.z, g4.w};
        #pragma unroll
        for (int s = 0; s < 4; ++s) {
            int p = p0 + s;
            int i = p / W;
            int j = p - i * W;
            float* bin = bins + ls[s] * 5;
            atomicAdd(bin + 0, fs[s]);
            atomicAdd(bin + 1, gs[s]);
            atomicAdd(bin + 2, (float)i * sx - 1.f);
            atomicAdd(bin + 3, (float)j * sy - 1.f);
            atomicAdd(bin + 4, 1.f);
        }
    }
    __syncthreads();

    float* outp = partial + (size_t)blockIdx.x * KB;
    for (int i = tid; i < KB; i += TPB) outp[i] = bins[i];
}

// -------------------- fusedA: reduce partials + mean + layer1 + bn1 stats --------------------
// Grid: N/64 blocks of 256 threads. Block handles 64 tokens.
// Threads are 4 groups (g=tid>>6) x 64 tokens (tt=tid&63): groups split the
// chunk reduction, then wave g computes channels [g*16, g*16+16) for all 64
// tokens, writes h1 channel-major, and butterfly-reduces bn1 sum/sumsq.
__global__ void fusedA_kernel(const float* __restrict__ partial,
                              const int* __restrict__ frame_idx,
                              const int* __restrict__ n_frames_p,
                              const float* __restrict__ conv_w,
                              const float* __restrict__ conv_b,
                              float* __restrict__ h1,
                              float* __restrict__ statsBuf,
                              int K, int N, int chunks) {
    __shared__ float red[TPB * 5];
    __shared__ float feat[64 * 5];
    __shared__ float cw[320];
    __shared__ float cb[64];
    const int tid = threadIdx.x;
    for (int i = tid; i < 320; i += TPB) cw[i] = conv_w[i];
    if (tid < 64) cb[tid] = conv_b[tid];

    const int g  = tid >> 6;
    const int tt = tid & 63;
    const int t  = blockIdx.x * 64 + tt;
    const bool valid = t < N;
    const int b = valid ? (t / K) : 0;
    const int k = t - b * K;

    float a0 = 0.f, a1 = 0.f, a2 = 0.f, a3 = 0.f, a4 = 0.f;
    if (valid) {
        #pragma unroll 4
        for (int ch = g; ch < chunks; ch += 4) {
            const float* p = partial + (((size_t)b * chunks + ch) * K + k) * 5;
            a0 += p[0]; a1 += p[1]; a2 += p[2]; a3 += p[3]; a4 += p[4];
        }
    }
    red[tid * 5 + 0] = a0; red[tid * 5 + 1] = a1; red[tid * 5 + 2] = a2;
    red[tid * 5 + 3] = a3; red[tid * 5 + 4] = a4;
    __syncthreads();

    if (g == 0) {
        float s0 = 0.f, s1 = 0.f, s2 = 0.f, s3 = 0.f, s4 = 0.f;
        #pragma unroll
        for (int q = 0; q < 4; ++q) {
            const float* r = red + (q * 64 + tt) * 5;
            s0 += r[0]; s1 += r[1]; s2 += r[2]; s3 += r[3]; s4 += r[4];
        }
        float inv = 1.f / fmaxf(s4, 1.f);
        float invnf = 1.f / (float)(n_frames_p[0] - 1);
        feat[tt * 5 + 0] = valid ? (float)frame_idx[b] * invnf : 0.f;
        feat[tt * 5 + 1] = s0 * inv;
        feat[tt * 5 + 2] = s1 * inv;
        feat[tt * 5 + 3] = s2 * inv;
        feat[tt * 5 + 4] = s3 * inv;
    }
    __syncthreads();

    const float x0 = feat[tt * 5 + 0], x1 = feat[tt * 5 + 1],
                x2 = feat[tt * 5 + 2], x3 = feat[tt * 5 + 3],
                x4 = feat[tt * 5 + 4];
    float hs[16];
    const int c0 = g * 16;
    #pragma unroll
    for (int j = 0; j < 16; ++j) {
        int c = c0 + j;
        const float* w = cw + c * 5;
        float h = cb[c] + w[0]*x0 + w[1]*x1 + w[2]*x2 + w[3]*x3 + w[4]*x4;
        hs[j] = valid ? h : 0.f;
        if (valid) h1[(size_t)c * N + t] = h;
    }

    // per-wave butterfly over 64 tokens, per channel; lane j keeps channel c0+j
    float mySum = 0.f, mySq = 0.f;
    #pragma unroll
    for (int j = 0; j < 16; ++j) {
        float s = hs[j];
        float q = hs[j] * hs[j];
        #pragma unroll
        for (int m = 1; m < 64; m <<= 1) {
            s += __shfl_xor(s, m, 64);
            q += __shfl_xor(q, m, 64);
        }
        if (tt == j) { mySum = s; mySq = q; }
    }
    if (tt < 16) {
        atomicAdd(statsBuf + c0 + tt, mySum);
        atomicAdd(statsBuf + 64 + c0 + tt, mySq);
    }
}

// -------------------- fusedB: fold bn1 + relu + layer2 + bn2 stats --------------------
__global__ void fusedB_kernel(const float* __restrict__ h1,
                              const float* __restrict__ bn1_g,
                              const float* __restrict__ bn1_b,
                              const float* __restrict__ lin_w,
                              const float* __restrict__ lin_b,
                              float* __restrict__ h2,
                              float* __restrict__ statsBuf,
                              int N) {
    __shared__ float w[2048];
    __shared__ float sc[64], sh[64], lb[32];
    const int tid = threadIdx.x;
    for (int i = tid; i < 2048; i += TPB) w[i] = lin_w[i];
    if (tid < 64) {
        float invN = 1.f / (float)N;
        float mean = statsBuf[tid] * invN;
        float var  = statsBuf[64 + tid] * invN - mean * mean;
        float s = bn1_g[tid] * rsqrtf(var + 1e-5f);
        sc[tid] = s;
        sh[tid] = bn1_b[tid] - mean * s;
    }
    if (tid < 32) lb[tid] = lin_b[tid];
    __syncthreads();

    const int t = blockIdx.x * TPB + tid;
    const bool valid = t < N;
    float y[64];
    if (valid) {
        #pragma unroll
        for (int c = 0; c < 64; ++c)
            y[c] = fmaxf(h1[(size_t)c * N + t] * sc[c] + sh[c], 0.f);
    } else {
        #pragma unroll
        for (int c = 0; c < 64; ++c) y[c] = 0.f;
    }

    float hs[32];
    #pragma unroll 4
    for (int o = 0; o < 32; ++o) {
        float acc = lb[o];
        const float* wo = w + o * 64;
        #pragma unroll
        for (int c = 0; c < 64; ++c) acc += wo[c] * y[c];
        hs[o] = valid ? acc : 0.f;
        if (valid) h2[(size_t)o * N + t] = acc;
    }

    const int lane = tid & 63;
    float mySum = 0.f, mySq = 0.f;
    #pragma unroll
    for (int o = 0; o < 32; ++o) {
        float s = hs[o];
        float q = hs[o] * hs[o];
        #pragma unroll
        for (int m = 1; m < 64; m <<= 1) {
            s += __shfl_xor(s, m, 64);
            q += __shfl_xor(q, m, 64);
        }
        if (lane == o) { mySum = s; mySq = q; }
    }
    if (lane < 32) {
        atomicAdd(statsBuf + 128 + lane, mySum);
        atomicAdd(statsBuf + 160 + lane, mySq);
    }
}

// -------------------- final: fold bn2 + relu + L2 normalize --------------------
__global__ void final_kernel(const float* __restrict__ h2,
                             const float* __restrict__ bn2_g,
                             const float* __restrict__ bn2_b,
                             const float* __restrict__ statsBuf,
                             float* __restrict__ out, int N) {
    __shared__ float sc[32], sh[32];
    const int tid = threadIdx.x;
    if (tid < 32) {
        float invN = 1.f / (float)N;
        float mean = statsBuf[128 + tid] * invN;
        float var  = statsBuf[160 + tid] * invN - mean * mean;
        float s = bn2_g[tid] * rsqrtf(var + 1e-5f);
        sc[tid] = s;
        sh[tid] = bn2_b[tid] - mean * s;
    }
    __syncthreads();

    const int t = blockIdx.x * TPB + tid;
    if (t >= N) return;
    float y[32];
    float ss = 0.f;
    #pragma unroll
    for (int o = 0; o < 32; ++o) {
        float v = fmaxf(h2[(size_t)o * N + t] * sc[o] + sh[o], 0.f);
        y[o] = v;
        ss += v * v;
    }
    float inv = 1.f / fmaxf(sqrtf(ss), 1e-8f);
    float4* o4 = (float4*)(out + (size_t)t * 32);
    #pragma unroll
    for (int q = 0; q < 8; ++q)
        o4[q] = make_float4(y[4*q+0]*inv, y[4*q+1]*inv, y[4*q+2]*inv, y[4*q+3]*inv);
}

extern "C" void kernel_launch(void* const* d_in, const int* in_sizes, int n_in,
                              void* d_out, int out_size, void* d_ws, size_t ws_size,
                              hipStream_t stream) {
    const int*   labels     = (const int*)d_in[0];
    const float* fx         = (const float*)d_in[1];
    const float* fy         = (const float*)d_in[2];
    const int*   frame_idx  = (const int*)d_in[3];
    const int*   n_frames_p = (const int*)d_in[4];
    // d_in[5] = n_labels (derived from out_size instead)
    const float* conv_w = (const float*)d_in[6];
    const float* conv_b = (const float*)d_in[7];
    const float* bn1_g  = (const float*)d_in[8];
    const float* bn1_b  = (const float*)d_in[9];
    const float* lin_w  = (const float*)d_in[10];
    const float* lin_b  = (const float*)d_in[11];
    const float* bn2_g  = (const float*)d_in[12];
    const float* bn2_b  = (const float*)d_in[13];
    float* out = (float*)d_out;

    const int B = in_sizes[3];                       // 16
    const int P = in_sizes[0] / B;                   // 262144
    const int W = (int)(sqrt((double)P) + 0.5);      // 512 (square image)
    const int H = P / W;
    const int K = out_size / (B * 32);               // 1024
    const int N = B * K;                             // 16384

    // workspace layout (floats): h1[64*N] | h2[32*N] | statsBuf[256] | partial[B*chunks*K*5]
    float* h1       = (float*)d_ws;
    float* h2       = h1 + (size_t)64 * N;
    float* statsBuf = h2 + (size_t)32 * N;
    float* partial  = statsBuf + 256;
    const size_t fixed_bytes = ((size_t)96 * N + 256) * sizeof(float);

    int chunks = 64;
    while (chunks > 1 &&
           ((size_t)B * chunks * K * 5 * sizeof(float) + fixed_bytes > ws_size ||
            (P % (chunks * 4)) != 0))
        chunks >>= 1;

    pool_kernel<<<B * chunks, TPB, (size_t)K * 5 * sizeof(float), stream>>>(
        labels, fx, fy, partial, statsBuf, K, H, W, chunks);
    fusedA_kernel<<<(N + 63) / 64, TPB, 0, stream>>>(
        partial, frame_idx, n_frames_p, conv_w, conv_b, h1, statsBuf, K, N, chunks);
    fusedB_kernel<<<(N + TPB - 1) / TPB, TPB, 0, stream>>>(
        h1, bn1_g, bn1_b, lin_w, lin_b, h2, statsBuf, N);
    final_kernel<<<(N + TPB - 1) / TPB, TPB, 0, stream>>>(
        h2, bn2_g, bn2_b, statsBuf, out, N);
}

// Round 3
// 176.983 us; speedup vs baseline: 1.7362x; 1.7362x over previous
//
#include <hip/hip_runtime.h>
#include <math.h>

#define TPB 256
#define FPSCALE 262144.0f          // 2^18 fixed-point scale for fx/fy sums
#define INV_FPSCALE (1.0f / 262144.0f)

// statsBuf layout (floats): [0:64) bn1 sum, [64:128) bn1 sumsq,
//                           [128:160) bn2 sum, [160:192) bn2 sumsq

// -------------------- segment pool: native-int LDS bins -> partial sums --------------------
// geo u64 per bin packs: count [0:16), sum_j [16:40), sum_i [40:64).
// fx/fy accumulate as 2^18 fixed-point int. All atomics are native integer DS ops.
__global__ void pool_kernel(const int* __restrict__ labels,
                            const float* __restrict__ fx,
                            const float* __restrict__ fy,
                            float* __restrict__ partial,
                            float* __restrict__ statsBuf,
                            int K, int H, int W, int wlog, int chunks) {
    extern __shared__ unsigned long long geo[];      // K u64
    int* fxb = (int*)(geo + K);                      // K int
    int* fyb = fxb + K;                              // K int
    const int P = H * W;
    const int b = blockIdx.x / chunks;
    const int chunk = blockIdx.x - b * chunks;
    const int chunkP = P / chunks;
    const int tid = threadIdx.x;

    if (blockIdx.x == 0 && tid < 192) statsBuf[tid] = 0.f;

    unsigned int* z = (unsigned int*)geo;
    for (int i = tid; i < K * 4; i += TPB) z[i] = 0u;
    __syncthreads();

    const size_t base = (size_t)b * P + (size_t)chunk * chunkP;
    const int4*   l4p  = (const int4*)(labels + base);
    const float4* fx4p = (const float4*)(fx + base);
    const float4* fy4p = (const float4*)(fy + base);
    const int nvec = chunkP >> 2;

    for (int v = tid; v < nvec; v += TPB) {
        int4   l4 = l4p[v];
        float4 f4 = fx4p[v];
        float4 g4 = fy4p[v];
        int p0 = chunk * chunkP + (v << 2);
        int   ls[4] = {l4.x, l4.y, l4.z, l4.w};
        float fs[4] = {f4.x, f4.y, f4.z, f4.w};
        float gs[4] = {g4.x, g4.y, g4.z, g4.w};
        #pragma unroll
        for (int s = 0; s < 4; ++s) {
            int p = p0 + s;
            int i, j;
            if (wlog >= 0) { i = p >> wlog; j = p & (W - 1); }
            else           { i = p / W;     j = p - i * W; }
            unsigned long long gadd = ((unsigned long long)i << 40)
                                    | ((unsigned long long)j << 16) | 1ull;
            atomicAdd(&geo[ls[s]], gadd);
            atomicAdd(&fxb[ls[s]], __float2int_rn(fs[s] * FPSCALE));
            atomicAdd(&fyb[ls[s]], __float2int_rn(gs[s] * FPSCALE));
        }
    }
    __syncthreads();

    const float sx = 2.f / (float)(H - 1);           // xx varies along dim 2 (i)
    const float sy = 2.f / (float)(W - 1);           // yy varies along dim 3 (j)
    float* outp = partial + (size_t)blockIdx.x * K * 5;
    for (int k = tid; k < K; k += TPB) {
        unsigned long long g = geo[k];
        float cnt = (float)(unsigned int)(g & 0xFFFFull);
        float sj  = (float)(unsigned int)((g >> 16) & 0xFFFFFFull);
        float si  = (float)(unsigned int)(g >> 40);
        float* p = outp + k * 5;
        p[0] = (float)fxb[k] * INV_FPSCALE;          // sum fx
        p[1] = (float)fyb[k] * INV_FPSCALE;          // sum fy
        p[2] = sx * si - cnt;                        // sum xx
        p[3] = sy * sj - cnt;                        // sum yy
        p[4] = cnt;                                  // count
    }
}

// -------------------- fusedA: coalesced reduce + mean + layer1 + bn1 stats --------------------
// Grid: N/64 blocks of 256 threads. Block reduces 320 contiguous floats per chunk
// slab (coalesced), then 4 groups x 64 tokens compute 16 channels each.
__global__ void fusedA_kernel(const float* __restrict__ partial,
                              const int* __restrict__ frame_idx,
                              const int* __restrict__ n_frames_p,
                              const float* __restrict__ conv_w,
                              const float* __restrict__ conv_b,
                              float* __restrict__ h1,
                              float* __restrict__ statsBuf,
                              int K, int N, int chunks) {
    __shared__ float red[320];
    __shared__ float feat[320];
    __shared__ float cw[320];
    __shared__ float cb[64];
    const int tid = threadIdx.x;
    for (int i = tid; i < 320; i += TPB) cw[i] = conv_w[i];
    if (tid < 64) cb[tid] = conv_b[tid];

    const int t0 = blockIdx.x * 64;
    const int b  = t0 / K;                            // 64 | K, so one batch per block
    const int k0 = t0 - b * K;

    float acc0 = 0.f, acc1 = 0.f;
    const float* pb = partial + ((size_t)b * chunks * K + k0) * 5;
    for (int ch = 0; ch < chunks; ++ch) {
        const float* pc = pb + (size_t)ch * K * 5;
        acc0 += pc[tid];
        if (tid < 64) acc1 += pc[256 + tid];
    }
    red[tid] = acc0;
    if (tid < 64) red[256 + tid] = acc1;
    __syncthreads();

    const int g  = tid >> 6;
    const int tt = tid & 63;
    const int t  = t0 + tt;
    const bool valid = t < N;
    if (g == 0) {
        const float* r = red + tt * 5;
        float inv = 1.f / fmaxf(r[4], 1.f);
        float invnf = 1.f / (float)(n_frames_p[0] - 1);
        feat[tt * 5 + 0] = valid ? (float)frame_idx[b] * invnf : 0.f;
        feat[tt * 5 + 1] = r[0] * inv;
        feat[tt * 5 + 2] = r[1] * inv;
        feat[tt * 5 + 3] = r[2] * inv;
        feat[tt * 5 + 4] = r[3] * inv;
    }
    __syncthreads();

    const float x0 = feat[tt * 5 + 0], x1 = feat[tt * 5 + 1],
                x2 = feat[tt * 5 + 2], x3 = feat[tt * 5 + 3],
                x4 = feat[tt * 5 + 4];
    float hs[16];
    const int c0 = g * 16;
    #pragma unroll
    for (int j = 0; j < 16; ++j) {
        int c = c0 + j;
        const float* w = cw + c * 5;
        float h = cb[c] + w[0]*x0 + w[1]*x1 + w[2]*x2 + w[3]*x3 + w[4]*x4;
        hs[j] = valid ? h : 0.f;
        if (valid) h1[(size_t)c * N + t] = h;
    }

    float mySum = 0.f, mySq = 0.f;
    #pragma unroll
    for (int j = 0; j < 16; ++j) {
        float s = hs[j];
        float q = hs[j] * hs[j];
        #pragma unroll
        for (int m = 1; m < 64; m <<= 1) {
            s += __shfl_xor(s, m, 64);
            q += __shfl_xor(q, m, 64);
        }
        if (tt == j) { mySum = s; mySq = q; }
    }
    if (tt < 16) {
        atomicAdd(statsBuf + c0 + tt, mySum);
        atomicAdd(statsBuf + 64 + c0 + tt, mySq);
    }
}

// -------------------- fusedB: fold bn1 + relu + layer2 + bn2 stats --------------------
// Grid: N/64 blocks. 4 groups x 64 tokens; group g computes outputs [g*8, g*8+8).
__global__ void fusedB_kernel(const float* __restrict__ h1,
                              const float* __restrict__ bn1_g,
                              const float* __restrict__ bn1_b,
                              const float* __restrict__ lin_w,
                              const float* __restrict__ lin_b,
                              float* __restrict__ h2,
                              float* __restrict__ statsBuf,
                              int N) {
    __shared__ float w[2048];
    __shared__ float sc[64], sh[64], lb[32];
    const int tid = threadIdx.x;
    for (int i = tid; i < 2048; i += TPB) w[i] = lin_w[i];
    if (tid < 64) {
        float invN = 1.f / (float)N;
        float mean = statsBuf[tid] * invN;
        float var  = statsBuf[64 + tid] * invN - mean * mean;
        float s = bn1_g[tid] * rsqrtf(var + 1e-5f);
        sc[tid] = s;
        sh[tid] = bn1_b[tid] - mean * s;
    }
    if (tid < 32) lb[tid] = lin_b[tid];
    __syncthreads();

    const int g  = tid >> 6;
    const int tt = tid & 63;
    const int t  = blockIdx.x * 64 + tt;
    const bool valid = t < N;
    float y[64];
    #pragma unroll
    for (int c = 0; c < 64; ++c)
        y[c] = valid ? fmaxf(h1[(size_t)c * N + t] * sc[c] + sh[c], 0.f) : 0.f;

    float hs[8];
    const int o0 = g * 8;
    #pragma unroll
    for (int j = 0; j < 8; ++j) {
        int o = o0 + j;
        const float* wo = w + o * 64;
        float acc = lb[o];
        #pragma unroll
        for (int c = 0; c < 64; ++c) acc += wo[c] * y[c];
        hs[j] = valid ? acc : 0.f;
        if (valid) h2[(size_t)o * N + t] = acc;
    }

    float mySum = 0.f, mySq = 0.f;
    #pragma unroll
    for (int j = 0; j < 8; ++j) {
        float s = hs[j];
        float q = hs[j] * hs[j];
        #pragma unroll
        for (int m = 1; m < 64; m <<= 1) {
            s += __shfl_xor(s, m, 64);
            q += __shfl_xor(q, m, 64);
        }
        if (tt == j) { mySum = s; mySq = q; }
    }
    if (tt < 8) {
        atomicAdd(statsBuf + 128 + o0 + tt, mySum);
        atomicAdd(statsBuf + 160 + o0 + tt, mySq);
    }
}

// -------------------- final: fold bn2 + relu + L2 normalize --------------------
// Grid: N/64 blocks. 4 groups x 64 tokens; cross-group sumsq via LDS; coalesced
// float4 stores through an LDS transpose tile.
__global__ void final_kernel(const float* __restrict__ h2,
                             const float* __restrict__ bn2_g,
                             const float* __restrict__ bn2_b,
                             const float* __restrict__ statsBuf,
                             float* __restrict__ out, int N) {
    __shared__ float sc[32], sh[32];
    __shared__ float vtile[32 * 65];
    __shared__ float ssqp[4 * 64];
    __shared__ float linv[64];
    const int tid = threadIdx.x;
    if (tid < 32) {
        float invN = 1.f / (float)N;
        float mean = statsBuf[128 + tid] * invN;
        float var  = statsBuf[160 + tid] * invN - mean * mean;
        float s = bn2_g[tid] * rsqrtf(var + 1e-5f);
        sc[tid] = s;
        sh[tid] = bn2_b[tid] - mean * s;
    }
    __syncthreads();

    const int g  = tid >> 6;
    const int tt = tid & 63;
    const int t  = blockIdx.x * 64 + tt;
    const bool valid = t < N;
    const int o0 = g * 8;
    float ss = 0.f;
    #pragma unroll
    for (int j = 0; j < 8; ++j) {
        int o = o0 + j;
        float v = valid ? fmaxf(h2[(size_t)o * N + t] * sc[o] + sh[o], 0.f) : 0.f;
        vtile[o * 65 + tt] = v;
        ss += v * v;
    }
    ssqp[g * 64 + tt] = ss;
    __syncthreads();
    if (g == 0) {
        float tot = ssqp[tt] + ssqp[64 + tt] + ssqp[128 + tt] + ssqp[192 + tt];
        linv[tt] = 1.f / fmaxf(sqrtf(tot), 1e-8f);
    }
    __syncthreads();

    const int nq = min(512, (N - blockIdx.x * 64) * 8);   // float4s this block owns
    float4* o4 = (float4*)(out + (size_t)blockIdx.x * 64 * 32);
    for (int q = tid; q < nq; q += TPB) {
        int tk = q >> 3;
        int oo = (q & 7) * 4;
        float iv = linv[tk];
        o4[q] = make_float4(vtile[(oo + 0) * 65 + tk] * iv,
                            vtile[(oo + 1) * 65 + tk] * iv,
                            vtile[(oo + 2) * 65 + tk] * iv,
                            vtile[(oo + 3) * 65 + tk] * iv);
    }
}

extern "C" void kernel_launch(void* const* d_in, const int* in_sizes, int n_in,
                              void* d_out, int out_size, void* d_ws, size_t ws_size,
                              hipStream_t stream) {
    const int*   labels     = (const int*)d_in[0];
    const float* fx         = (const float*)d_in[1];
    const float* fy         = (const float*)d_in[2];
    const int*   frame_idx  = (const int*)d_in[3];
    const int*   n_frames_p = (const int*)d_in[4];
    // d_in[5] = n_labels (derived from out_size instead)
    const float* conv_w = (const float*)d_in[6];
    const float* conv_b = (const float*)d_in[7];
    const float* bn1_g  = (const float*)d_in[8];
    const float* bn1_b  = (const float*)d_in[9];
    const float* lin_w  = (const float*)d_in[10];
    const float* lin_b  = (const float*)d_in[11];
    const float* bn2_g  = (const float*)d_in[12];
    const float* bn2_b  = (const float*)d_in[13];
    float* out = (float*)d_out;

    const int B = in_sizes[3];                       // 16
    const int P = in_sizes[0] / B;                   // 262144
    const int W = (int)(sqrt((double)P) + 0.5);      // 512 (square image)
    const int H = P / W;
    const int K = out_size / (B * 32);               // 1024
    const int N = B * K;                             // 16384

    int wlog = -1;
    if ((W & (W - 1)) == 0) { wlog = 0; while ((1 << wlog) < W) ++wlog; }

    // workspace layout (floats): h1[64*N] | h2[32*N] | statsBuf[256] | partial[B*chunks*K*5]
    float* h1       = (float*)d_ws;
    float* h2       = h1 + (size_t)64 * N;
    float* statsBuf = h2 + (size_t)32 * N;
    float* partial  = statsBuf + 256;
    const size_t fixed_bytes = ((size_t)96 * N + 256) * sizeof(float);

    int chunks = 64;
    while (chunks > 1 &&
           ((size_t)B * chunks * K * 5 * sizeof(float) + fixed_bytes > ws_size ||
            (P % (chunks * 4)) != 0))
        chunks >>= 1;
    while (P / chunks > 32768) chunks <<= 1;         // keep u64 geo fields safe

    pool_kernel<<<B * chunks, TPB, (size_t)K * 16, stream>>>(
        labels, fx, fy, partial, statsBuf, K, H, W, wlog, chunks);
    fusedA_kernel<<<(N + 63) / 64, TPB, 0, stream>>>(
        partial, frame_idx, n_frames_p, conv_w, conv_b, h1, statsBuf, K, N, chunks);
    fusedB_kernel<<<(N + 63) / 64, TPB, 0, stream>>>(
        h1, bn1_g, bn1_b, lin_w, lin_b, h2, statsBuf, N);
    final_kernel<<<(N + 63) / 64, TPB, 0, stream>>>(
        h2, bn2_g, bn2_b, statsBuf, out, N);
}